// Round 7
// baseline (497.546 us; speedup 1.0000x reference)
//
#include <hip/hip_runtime.h>
#include <math.h>

#define IN_DIM 256
#define HID 128
#define OUTD 32
#define NEG_SLOPE 0.2f
#define BSH 8                 // 256 dst nodes per bucket
#define EPB 4096              // edges per binning block

typedef unsigned short ushort_t;
typedef unsigned int uint_t;
typedef __attribute__((ext_vector_type(8))) short short8;
typedef __attribute__((ext_vector_type(4))) float f32x4;
typedef int int4_u __attribute__((ext_vector_type(4), aligned(8)));  // 8B-aligned 2x epk record

__device__ __forceinline__ ushort_t f2b(float f) {
    union { float f; uint_t i; } v; v.f = f;
    uint_t x = v.i;
    uint_t r = (x + 0x7FFFu + ((x >> 16) & 1u)) >> 16;   // RNE
    return (ushort_t)r;
}

__device__ __forceinline__ float b2f(ushort_t b) {
    union { uint_t i; float f; } v; v.i = ((uint_t)b) << 16;
    return v.f;
}

// ---------------------------------------------------------------------------
// swizzle weights into MFMA B-fragment order (bf16).
// B-frag layout for 16x16x32: lane l holds B[k][n], n=16*tile+(l&15), k=32*step+(l>>4)*8+j
// ---------------------------------------------------------------------------
__global__ __launch_bounds__(256) void swz_kernel(
    const float* __restrict__ W1, const float* __restrict__ W2,
    ushort_t* __restrict__ W1B, ushort_t* __restrict__ W1TB, ushort_t* __restrict__ W2TB)
{
    int idx = blockIdx.x * 256 + threadIdx.x;
    if (idx < 32768) {
        int j = idx & 7, l = (idx >> 3) & 63, t = (idx >> 9) & 7, s = idx >> 12;
        int n = 16 * t + (l & 15), k = 32 * s + (l >> 4) * 8 + j;
        W1B[idx] = f2b(W1[k * HID + n]);
    } else if (idx < 65536) {
        int o = idx - 32768;
        int j = o & 7, l = (o >> 3) & 63, t = (o >> 9) & 15, s = o >> 13;
        int n = 16 * t + (l & 15), k = 32 * s + (l >> 4) * 8 + j;
        W1TB[o] = f2b(W1[n * HID + k]);
    } else if (idx < 69632) {
        int o = idx - 65536;
        int j = o & 7, l = (o >> 3) & 63, t = o >> 9;
        int n = 16 * t + (l & 15), k = (l >> 4) * 8 + j;
        W2TB[o] = f2b(W2[n * OUTD + k]);
    }
}

// ---------------------------------------------------------------------------
// gemm1 (MFMA): xs1 = x @ W1 [N,256]x[256,128] + fused as1/ad1 attention dots.
// f32 x converted to bf16 during LDS staging; bf16 xs1 out.
// ---------------------------------------------------------------------------
__global__ __launch_bounds__(256) void gemm1_mfma(
    const float* __restrict__ x, const ushort_t* __restrict__ W1B,
    const float* __restrict__ a_src, const float* __restrict__ a_dst,
    ushort_t* __restrict__ xs1b, float* __restrict__ as1, float* __restrict__ ad1, int N)
{
    __shared__ ushort_t lx[64 * 264];          // 256+8 pad: 2-way bank alias only
    const int tid = threadIdx.x;
    const int row0 = blockIdx.x * 64;
    const int nrows = min(64, N - row0);

    for (int i = tid; i < nrows * 32; i += 256) {
        int r = i >> 5, c = i & 31;
        const float* p = x + (size_t)(row0 + r) * IN_DIM + c * 8;
        float4 v0 = *(const float4*)p;
        float4 v1 = *(const float4*)(p + 4);
        ushort_t o[8] = { f2b(v0.x), f2b(v0.y), f2b(v0.z), f2b(v0.w),
                          f2b(v1.x), f2b(v1.y), f2b(v1.z), f2b(v1.w) };
        *(uint4*)(&lx[r * 264 + c * 8]) = *(uint4*)o;
    }
    __syncthreads();

    const int wave = tid >> 6, lane = tid & 63;
    const int lo = lane & 15, q = lane >> 4;
    f32x4 acc[8];
    #pragma unroll
    for (int t = 0; t < 8; t++) acc[t] = (f32x4){0.f, 0.f, 0.f, 0.f};

    const int arow = wave * 16 + lo;
    #pragma unroll
    for (int s = 0; s < 8; s++) {
        short8 af = *(const short8*)(&lx[arow * 264 + s * 32 + q * 8]);
        #pragma unroll
        for (int t = 0; t < 8; t++) {
            short8 bf = *(const short8*)(W1B + ((size_t)(s * 8 + t) * 64 + lane) * 8);
            acc[t] = __builtin_amdgcn_mfma_f32_16x16x32_bf16(af, bf, acc[t], 0, 0, 0);
        }
    }

    // attention logits: vs[m] = sum_n xs1[m][n]*a_src[n].  C layout: row=q*4+r, col=lo.
    float asv[8], adv[8];
    #pragma unroll
    for (int t = 0; t < 8; t++) { asv[t] = a_src[t * 16 + lo]; adv[t] = a_dst[t * 16 + lo]; }
    #pragma unroll
    for (int r = 0; r < 4; r++) {
        float vs = 0.f, vd = 0.f;
        #pragma unroll
        for (int t = 0; t < 8; t++) { vs += acc[t][r] * asv[t]; vd += acc[t][r] * adv[t]; }
        #pragma unroll
        for (int off = 1; off < 16; off <<= 1) {       // reduce over lo (stays in q-group)
            vs += __shfl_xor(vs, off, 64);
            vd += __shfl_xor(vd, off, 64);
        }
        int m = row0 + wave * 16 + q * 4 + r;
        if (lo == 0 && m < N) { as1[m] = vs; ad1[m] = vd; }
    }

    #pragma unroll
    for (int r = 0; r < 4; r++) {
        int m = row0 + wave * 16 + q * 4 + r;
        if (m < N) {
            #pragma unroll
            for (int t = 0; t < 8; t++)
                xs1b[(size_t)m * HID + t * 16 + lo] = f2b(acc[t][r]);
        }
    }
}

// ---------------------------------------------------------------------------
// gemm3g (MFMA): h3 = elu( g @ W2^T ) [N,32]x[32,128]; K=32; bf16 out.
// ---------------------------------------------------------------------------
__global__ __launch_bounds__(256) void gemm3g_mfma(
    const ushort_t* __restrict__ gb, const ushort_t* __restrict__ W2TB,
    ushort_t* __restrict__ h3b, int N)
{
    __shared__ ushort_t lh[64 * 40];           // 32+8 pad
    const int tid = threadIdx.x;
    const int row0 = blockIdx.x * 64;
    const int nrows = min(64, N - row0);
    for (int i = tid; i < nrows * 4; i += 256) {
        int r = i >> 2, c = i & 3;
        *(uint4*)(&lh[r * 40 + c * 8]) =
            *(const uint4*)(gb + (size_t)(row0 + r) * OUTD + c * 8);
    }
    __syncthreads();

    const int wave = tid >> 6, lane = tid & 63;
    const int lo = lane & 15, q = lane >> 4;
    f32x4 acc[8];
    #pragma unroll
    for (int t = 0; t < 8; t++) acc[t] = (f32x4){0.f, 0.f, 0.f, 0.f};
    short8 af = *(const short8*)(&lh[(wave * 16 + lo) * 40 + q * 8]);
    #pragma unroll
    for (int t = 0; t < 8; t++) {
        short8 bf = *(const short8*)(W2TB + ((size_t)t * 64 + lane) * 8);
        acc[t] = __builtin_amdgcn_mfma_f32_16x16x32_bf16(af, bf, acc[t], 0, 0, 0);
    }
    #pragma unroll
    for (int r = 0; r < 4; r++) {
        int m = row0 + wave * 16 + q * 4 + r;
        if (m < N) {
            #pragma unroll
            for (int t = 0; t < 8; t++) {
                float v = acc[t][r];
                v = v > 0.f ? v : expm1f(v);
                h3b[(size_t)m * HID + t * 16 + lo] = f2b(v);
            }
        }
    }
}

// ---------------------------------------------------------------------------
// gemm4 (MFMA): h4 = h3 @ W1^T [N,128]x[128,256]
// ---------------------------------------------------------------------------
__global__ __launch_bounds__(256) void gemm4_mfma(
    const ushort_t* __restrict__ h3b, const ushort_t* __restrict__ W1TB,
    float* __restrict__ h4, int N)
{
    __shared__ ushort_t lh[64 * 136];          // 128+8 pad
    const int tid = threadIdx.x;
    const int row0 = blockIdx.x * 64;
    const int nrows = min(64, N - row0);
    for (int i = tid; i < nrows * 16; i += 256) {
        int r = i >> 4, c = i & 15;
        *(uint4*)(&lh[r * 136 + c * 8]) =
            *(const uint4*)(h3b + (size_t)(row0 + r) * HID + c * 8);
    }
    __syncthreads();

    const int wave = tid >> 6, lane = tid & 63;
    const int lo = lane & 15, q = lane >> 4;
    f32x4 acc[16];
    #pragma unroll
    for (int t = 0; t < 16; t++) acc[t] = (f32x4){0.f, 0.f, 0.f, 0.f};
    const int arow = wave * 16 + lo;
    #pragma unroll
    for (int s = 0; s < 4; s++) {
        short8 af = *(const short8*)(&lh[arow * 136 + s * 32 + q * 8]);
        #pragma unroll
        for (int t = 0; t < 16; t++) {
            short8 bf = *(const short8*)(W1TB + ((size_t)(s * 16 + t) * 64 + lane) * 8);
            acc[t] = __builtin_amdgcn_mfma_f32_16x16x32_bf16(af, bf, acc[t], 0, 0, 0);
        }
    }
    #pragma unroll
    for (int r = 0; r < 4; r++) {
        int m = row0 + wave * 16 + q * 4 + r;
        if (m < N) {
            #pragma unroll
            for (int t = 0; t < 16; t++)
                h4[(size_t)m * IN_DIM + t * 16 + lo] = acc[t][r];
        }
    }
}

// ---------------------------------------------------------------------------
// Bucket-binned CSR build. bsort computes raw edge weights (one lane/edge),
// per-dst sums in LDS, and writes winv[d]=1/sum; aggs scale once at the end.
// ---------------------------------------------------------------------------
__global__ __launch_bounds__(256) void bhist_kernel(
    const int* __restrict__ dst, int* __restrict__ bcnt, int E, int B)
{
    __shared__ int lcnt[512];                 // B <= 512 (N <= 131072)
    int t = threadIdx.x;
    for (int i = t; i < B; i += 256) lcnt[i] = 0;
    __syncthreads();
    int base = blockIdx.x * EPB;
    int end = min(base + EPB, E);
    for (int e = base + t; e < end; e += 256)
        atomicAdd(&lcnt[dst[e] >> BSH], 1);
    __syncthreads();
    for (int i = t; i < B; i += 256) {
        int c = lcnt[i];
        if (c) atomicAdd(&bcnt[i], c);
    }
}

__global__ __launch_bounds__(512) void bscan_kernel(
    const int* __restrict__ bcnt, int* __restrict__ boff, int* __restrict__ gcur,
    int* __restrict__ off, int B, int N, int E)
{
    __shared__ int l[512];
    int t = threadIdx.x;
    int v = (t < B) ? bcnt[t] : 0;
    l[t] = v;
    __syncthreads();
    for (int o = 1; o < 512; o <<= 1) {
        int u = (t >= o) ? l[t - o] : 0;
        __syncthreads();
        l[t] += u;
        __syncthreads();
    }
    int pre = l[t] - v;                        // exclusive prefix
    if (t < B) { boff[t] = pre; gcur[t] = pre; }
    if (t == B - 1) boff[B] = pre + v;         // == E
    if (t == 0) off[N] = E;
}

__global__ __launch_bounds__(256) void bscatter_kernel(
    const int* __restrict__ src, const int* __restrict__ dst,
    int* __restrict__ gcur, int2* __restrict__ barr, int E, int B)
{
    __shared__ int lpos[512];
    int t = threadIdx.x;
    for (int i = t; i < B; i += 256) lpos[i] = 0;
    __syncthreads();
    int base = blockIdx.x * EPB;
    int end = min(base + EPB, E);
    for (int e = base + t; e < end; e += 256)
        atomicAdd(&lpos[dst[e] >> BSH], 1);
    __syncthreads();
    for (int i = t; i < B; i += 256) {
        int c = lpos[i];
        if (c) lpos[i] = atomicAdd(&gcur[i], c);   // count -> reserved base
    }
    __syncthreads();
    for (int e = base + t; e < end; e += 256) {
        int s = src[e], d = dst[e];
        int p = atomicAdd(&lpos[d >> BSH], 1);
        barr[p] = make_int2(s, d);
    }
}

__global__ __launch_bounds__(256) void bsort_kernel(
    const int2* __restrict__ barr, const int* __restrict__ boff,
    const float* __restrict__ as1, const float* __restrict__ ad1,
    int* __restrict__ off, int2* __restrict__ epk, float* __restrict__ winv, int N)
{
    __shared__ int ldeg[256];
    __shared__ int lscan[256];
    __shared__ float lsum[256];
    int b = blockIdx.x, t = threadIdx.x;
    int d0 = b << BSH;
    int e0 = boff[b], e1 = boff[b + 1];
    ldeg[t] = 0;
    lsum[t] = 0.f;
    __syncthreads();
    for (int e = e0 + t; e < e1; e += 256)
        atomicAdd(&ldeg[barr[e].y & 255], 1);
    __syncthreads();
    int my = ldeg[t];
    lscan[t] = my;
    __syncthreads();
    for (int o = 1; o < 256; o <<= 1) {
        int u = (t >= o) ? lscan[t - o] : 0;
        __syncthreads();
        lscan[t] += u;
        __syncthreads();
    }
    int pre = lscan[t] - my;                   // exclusive prefix within bucket
    int d = d0 + t;
    if (d < N) off[d] = e0 + pre;
    ldeg[t] = pre;                             // reuse as scatter cursor
    __syncthreads();
    for (int e = e0 + t; e < e1; e += 256) {
        int2 r = barr[e];
        float v = as1[r.x] + ad1[r.y];
        v = v > 0.f ? v : NEG_SLOPE * v;
        float w = __expf(v);                   // no max-subtraction: logits O(1)
        int p = atomicAdd(&ldeg[r.y & 255], 1);
        epk[e0 + p] = make_int2(r.x, __float_as_int(w));
        atomicAdd(&lsum[r.y & 255], w);        // ds_add_f32
    }
    __syncthreads();
    if (d < N) {
        float s = lsum[t];
        winv[d] = (my > 0 && s > 0.f) ? 1.0f / s : 0.f;
    }
}

// ---------------------------------------------------------------------------
// agg1 (128 cols): wave per dst; 4 edge-groups x 16 lanes; contiguous edge
// pairs per group. v_perm pairs two edges' bf16 at each column;
// v_dot2_f32_bf16 does 2 MACs/instr (inline asm -- builtin gate is absent on
// this toolchain, R6 evidence). Weights raw; normalize once via winv[d].
// Fused elu; f32 out.
// ---------------------------------------------------------------------------
__global__ __launch_bounds__(256) void agg128_kernel(
    const ushort_t* __restrict__ xsb, const int* __restrict__ off,
    const int2* __restrict__ epk, const float* __restrict__ winv,
    float* __restrict__ outf, int N)
{
    int d = blockIdx.x * 4 + (threadIdx.x >> 6);
    if (d >= N) return;
    const int lane = threadIdx.x & 63;
    const int g = lane >> 4, li = lane & 15;
    const int e0 = off[d], e1 = off[d + 1];
    const float wi = winv[d];

    float acc[8];
    #pragma unroll
    for (int j = 0; j < 8; j++) acc[j] = 0.f;

    int e = e0 + 2 * g;
    for (; e + 1 < e1; e += 8) {
        int4_u pp = *(const int4_u*)(epk + e);       // 2 records: (s0,w0,s1,w1)
        uint_t wpair;
        asm("v_cvt_pk_bf16_f32 %0, %1, %2"
            : "=v"(wpair)
            : "v"(__int_as_float(pp.y)), "v"(__int_as_float(pp.w)));
        uint4 u0 = *(const uint4*)(xsb + (size_t)pp.x * HID + li * 8);
        uint4 u1 = *(const uint4*)(xsb + (size_t)pp.z * HID + li * 8);
        uint_t pr;
        // lo halves -> (u0.lo16, u1.lo16); hi halves -> (u0.hi16, u1.hi16)
        pr = __builtin_amdgcn_perm(u0.x, u1.x, 0x01000504u);
        asm("v_dot2_f32_bf16 %0, %1, %2, %0" : "+v"(acc[0]) : "v"(pr), "v"(wpair));
        pr = __builtin_amdgcn_perm(u0.x, u1.x, 0x03020706u);
        asm("v_dot2_f32_bf16 %0, %1, %2, %0" : "+v"(acc[1]) : "v"(pr), "v"(wpair));
        pr = __builtin_amdgcn_perm(u0.y, u1.y, 0x01000504u);
        asm("v_dot2_f32_bf16 %0, %1, %2, %0" : "+v"(acc[2]) : "v"(pr), "v"(wpair));
        pr = __builtin_amdgcn_perm(u0.y, u1.y, 0x03020706u);
        asm("v_dot2_f32_bf16 %0, %1, %2, %0" : "+v"(acc[3]) : "v"(pr), "v"(wpair));
        pr = __builtin_amdgcn_perm(u0.z, u1.z, 0x01000504u);
        asm("v_dot2_f32_bf16 %0, %1, %2, %0" : "+v"(acc[4]) : "v"(pr), "v"(wpair));
        pr = __builtin_amdgcn_perm(u0.z, u1.z, 0x03020706u);
        asm("v_dot2_f32_bf16 %0, %1, %2, %0" : "+v"(acc[5]) : "v"(pr), "v"(wpair));
        pr = __builtin_amdgcn_perm(u0.w, u1.w, 0x01000504u);
        asm("v_dot2_f32_bf16 %0, %1, %2, %0" : "+v"(acc[6]) : "v"(pr), "v"(wpair));
        pr = __builtin_amdgcn_perm(u0.w, u1.w, 0x03020706u);
        asm("v_dot2_f32_bf16 %0, %1, %2, %0" : "+v"(acc[7]) : "v"(pr), "v"(wpair));
    }
    if (e < e1) {
        int2 p0 = epk[e];
        float w0 = __int_as_float(p0.y);
        uint4 u0 = *(const uint4*)(xsb + (size_t)p0.x * HID + li * 8);
        acc[0] += w0 * __uint_as_float(u0.x << 16);
        acc[1] += w0 * __uint_as_float(u0.x & 0xFFFF0000u);
        acc[2] += w0 * __uint_as_float(u0.y << 16);
        acc[3] += w0 * __uint_as_float(u0.y & 0xFFFF0000u);
        acc[4] += w0 * __uint_as_float(u0.z << 16);
        acc[5] += w0 * __uint_as_float(u0.z & 0xFFFF0000u);
        acc[6] += w0 * __uint_as_float(u0.w << 16);
        acc[7] += w0 * __uint_as_float(u0.w & 0xFFFF0000u);
    }

    #pragma unroll
    for (int j = 0; j < 8; j++) {
        acc[j] += __shfl_xor(acc[j], 16, 64);
        acc[j] += __shfl_xor(acc[j], 32, 64);
    }
    if (g != 0) return;
    float o[8];
    #pragma unroll
    for (int j = 0; j < 8; j++) {
        float v = acc[j] * wi;
        o[j] = v > 0.f ? v : expm1f(v);
    }
    float4 o0 = make_float4(o[0], o[1], o[2], o[3]);
    float4 o1 = make_float4(o[4], o[5], o[6], o[7]);
    *(float4*)(outf + (size_t)d * HID + li * 8) = o0;
    *(float4*)(outf + (size_t)d * HID + li * 8 + 4) = o1;
}

// ---------------------------------------------------------------------------
// agg2 (32 cols, on h2): wave per dst; 16 edge-groups x 4 lanes (uint4 each).
// Raw weights + winv scale. Output g (bf16) feeds gemm3g. No elu here.
// ---------------------------------------------------------------------------
__global__ __launch_bounds__(256) void agg32_kernel(
    const ushort_t* __restrict__ h2b, const int* __restrict__ off,
    const int2* __restrict__ epk, const float* __restrict__ winv,
    ushort_t* __restrict__ gb, int N)
{
    int d = blockIdx.x * 4 + (threadIdx.x >> 6);
    if (d >= N) return;
    const int lane = threadIdx.x & 63;
    const int g = lane >> 2, li = lane & 3;
    const int e0 = off[d], e1 = off[d + 1];
    const float wi = winv[d];

    float acc[8];
    #pragma unroll
    for (int j = 0; j < 8; j++) acc[j] = 0.f;

    for (int e = e0 + g; e < e1; e += 16) {
        int2 p = epk[e];
        float w = __int_as_float(p.y);
        uint4 u = *(const uint4*)(h2b + (size_t)p.x * OUTD + li * 8);
        acc[0] += w * __uint_as_float(u.x << 16);
        acc[1] += w * __uint_as_float(u.x & 0xFFFF0000u);
        acc[2] += w * __uint_as_float(u.y << 16);
        acc[3] += w * __uint_as_float(u.y & 0xFFFF0000u);
        acc[4] += w * __uint_as_float(u.z << 16);
        acc[5] += w * __uint_as_float(u.z & 0xFFFF0000u);
        acc[6] += w * __uint_as_float(u.w << 16);
        acc[7] += w * __uint_as_float(u.w & 0xFFFF0000u);
    }

    #pragma unroll
    for (int j = 0; j < 8; j++) {
        acc[j] += __shfl_xor(acc[j], 4, 64);
        acc[j] += __shfl_xor(acc[j], 8, 64);
        acc[j] += __shfl_xor(acc[j], 16, 64);
        acc[j] += __shfl_xor(acc[j], 32, 64);
    }
    if (g != 0) return;
    ushort_t ob[8] = { f2b(acc[0] * wi), f2b(acc[1] * wi), f2b(acc[2] * wi), f2b(acc[3] * wi),
                       f2b(acc[4] * wi), f2b(acc[5] * wi), f2b(acc[6] * wi), f2b(acc[7] * wi) };
    *(uint4*)(gb + (size_t)d * OUTD + li * 8) = *(uint4*)ob;
}

// ---------------------------------------------------------------------------
// gemm2: h2 = h1 @ W2 [N,128]x[128,32], f32 (accuracy) + bf16 copy for agg2
// ---------------------------------------------------------------------------
__global__ __launch_bounds__(256) void gemm2_kernel(
    const float* __restrict__ h1, const float* __restrict__ W2,
    float* __restrict__ h2, ushort_t* __restrict__ h2b, int N)
{
    __shared__ float lh[32 * 129];
    const int tid = threadIdx.x;
    const int row0 = blockIdx.x * 32;
    const int nrows = min(32, N - row0);
    for (int i = tid; i < nrows * 32; i += 256) {
        int r = i >> 5, q = i & 31;
        float4 v = *(const float4*)(h1 + (size_t)(row0 + r) * HID + q * 4);
        float* d = &lh[r * 129 + q * 4];
        d[0] = v.x; d[1] = v.y; d[2] = v.z; d[3] = v.w;
    }
    __syncthreads();
    const int r = tid >> 3;
    const int c0 = (tid & 7) * 4;
    float a0 = 0, a1 = 0, a2 = 0, a3 = 0;
    for (int k = 0; k < HID; k++) {
        float h = lh[r * 129 + k];
        float4 w = *(const float4*)(W2 + k * OUTD + c0);
        a0 += h * w.x; a1 += h * w.y; a2 += h * w.z; a3 += h * w.w;
    }
    if (r < nrows) {
        float4 o; o.x = a0; o.y = a1; o.z = a2; o.w = a3;
        *(float4*)(h2 + (size_t)(row0 + r) * OUTD + c0) = o;
        ushort_t ob[4] = { f2b(a0), f2b(a1), f2b(a2), f2b(a3) };
        *(uint2*)(h2b + (size_t)(row0 + r) * OUTD + c0) = *(uint2*)ob;
    }
}

extern "C" void kernel_launch(void* const* d_in, const int* in_sizes, int n_in,
                              void* d_out, int out_size, void* d_ws, size_t ws_size,
                              hipStream_t stream)
{
    const float* x     = (const float*)d_in[0];
    const float* W1    = (const float*)d_in[1];
    const float* a_src = (const float*)d_in[2];
    const float* a_dst = (const float*)d_in[3];
    const float* W2    = (const float*)d_in[4];
    const int*   ei    = (const int*)d_in[5];

    const int N = in_sizes[0] / IN_DIM;
    const int E = in_sizes[5] / 2;
    const int* src = ei;
    const int* dst = ei + E;
    const int B = (N + 255) >> BSH;            // buckets of 256 dst nodes

    float* ws = (float*)d_ws;
    size_t o = 0;
    ushort_t* A   = (ushort_t*)(ws + o); o += (size_t)N * HID / 2;   // xs1b; later gb
    float* Bb  = ws + o; o += (size_t)N * HID;        // h1 (f32)
    float* as1 = ws + o; o += N;
    float* ad1 = ws + o; o += N;
    float* winv = ws + o; o += N;
    ushort_t* h3b  = (ushort_t*)(ws + o); o += (size_t)N * HID / 2;   // bf16 h3
    ushort_t* h2b  = (ushort_t*)(ws + o); o += (size_t)N * OUTD / 2;  // bf16 h2
    ushort_t* W1B  = (ushort_t*)(ws + o); o += 16384;
    ushort_t* W1TB = (ushort_t*)(ws + o); o += 16384;
    ushort_t* W2TB = (ushort_t*)(ws + o); o += 2048;
    int2* barr = (int2*)(ws + o); o += (size_t)E * 2;  // packed (src,dst)
    int2* epk  = (int2*)(ws + o); o += (size_t)E * 2;  // packed (src, w_raw)
    int* off  = (int*)(ws + o);
    int* bcnt = off + N + 1;
    int* boff = bcnt + B;
    int* gcur = boff + B + 1;

    float* h2 = (float*)d_out;                 // [N,32]
    float* h4 = h2 + (size_t)N * OUTD;         // [N,256]

    hipMemsetAsync(bcnt, 0, (size_t)B * sizeof(int), stream);

    swz_kernel<<<(69632 + 255) / 256, 256, 0, stream>>>(W1, W2, W1B, W1TB, W2TB);

    // gemm1 (produces as1/ad1 needed by bsort) + bucket binning
    gemm1_mfma<<<(N + 63) / 64, 256, 0, stream>>>(x, W1B, a_src, a_dst, A, as1, ad1, N);

    const int GB = (E + EPB - 1) / EPB;
    bhist_kernel<<<GB, 256, 0, stream>>>(dst, bcnt, E, B);
    bscan_kernel<<<1, 512, 0, stream>>>(bcnt, boff, gcur, off, B, N, E);
    bscatter_kernel<<<GB, 256, 0, stream>>>(src, dst, gcur, barr, E, B);
    bsort_kernel<<<B, 256, 0, stream>>>(barr, boff, as1, ad1, off, epk, winv, N);

    // conv1 aggregate -> h1 (f32), gemm2 -> h2 (f32 out) + h2b (bf16)
    agg128_kernel<<<(N + 3) / 4, 256, 0, stream>>>(A, off, epk, winv, Bb, N);
    gemm2_kernel<<<(N + 31) / 32, 256, 0, stream>>>(Bb, W2, h2, h2b, N);

    // conv3: aggregate h2 (32 cols) -> g, then h3 = elu(g @ W2^T), gemm4 -> h4
    ushort_t* gb = A;                          // xs1b dead after agg128
    agg32_kernel<<<(N + 3) / 4, 256, 0, stream>>>(h2b, off, epk, winv, gb, N);
    gemm3g_mfma<<<(N + 63) / 64, 256, 0, stream>>>(gb, W2TB, h3b, N);
    gemm4_mfma<<<(N + 63) / 64, 256, 0, stream>>>(h3b, W1TB, h4, N);
}

// Round 8
// 491.069 us; speedup vs baseline: 1.0132x; 1.0132x over previous
//
#include <hip/hip_runtime.h>
#include <math.h>

#define IN_DIM 256
#define HID 128
#define OUTD 32
#define NEG_SLOPE 0.2f
#define BSH 8                 // 256 dst nodes per bucket
#define EPB 4096              // edges per binning block

typedef unsigned short ushort_t;
typedef unsigned int uint_t;
typedef __attribute__((ext_vector_type(8))) short short8;
typedef __attribute__((ext_vector_type(4))) float f32x4;
typedef int int4_u __attribute__((ext_vector_type(4), aligned(8)));  // 8B-aligned 2x epk record

__device__ __forceinline__ ushort_t f2b(float f) {
    union { float f; uint_t i; } v; v.f = f;
    uint_t x = v.i;
    uint_t r = (x + 0x7FFFu + ((x >> 16) & 1u)) >> 16;   // RNE
    return (ushort_t)r;
}

__device__ __forceinline__ float b2f(ushort_t b) {
    union { uint_t i; float f; } v; v.i = ((uint_t)b) << 16;
    return v.f;
}

// ---------------------------------------------------------------------------
// swizzle weights into MFMA B-fragment order (bf16).
// B-frag layout for 16x16x32: lane l holds B[k][n], n=16*tile+(l&15), k=32*step+(l>>4)*8+j
// ---------------------------------------------------------------------------
__global__ __launch_bounds__(256) void swz_kernel(
    const float* __restrict__ W1, const float* __restrict__ W2,
    ushort_t* __restrict__ W1B, ushort_t* __restrict__ W1TB, ushort_t* __restrict__ W2TB)
{
    int idx = blockIdx.x * 256 + threadIdx.x;
    if (idx < 32768) {
        int j = idx & 7, l = (idx >> 3) & 63, t = (idx >> 9) & 7, s = idx >> 12;
        int n = 16 * t + (l & 15), k = 32 * s + (l >> 4) * 8 + j;
        W1B[idx] = f2b(W1[k * HID + n]);
    } else if (idx < 65536) {
        int o = idx - 32768;
        int j = o & 7, l = (o >> 3) & 63, t = (o >> 9) & 15, s = o >> 13;
        int n = 16 * t + (l & 15), k = 32 * s + (l >> 4) * 8 + j;
        W1TB[o] = f2b(W1[n * HID + k]);
    } else if (idx < 69632) {
        int o = idx - 65536;
        int j = o & 7, l = (o >> 3) & 63, t = o >> 9;
        int n = 16 * t + (l & 15), k = (l >> 4) * 8 + j;
        W2TB[o] = f2b(W2[n * OUTD + k]);
    }
}

// ---------------------------------------------------------------------------
// gemm1 (MFMA): xs1 = x @ W1 [N,256]x[256,128] + fused as1/ad1 attention dots.
// f32 x converted to bf16 during LDS staging; bf16 xs1 out.
// ---------------------------------------------------------------------------
__global__ __launch_bounds__(256) void gemm1_mfma(
    const float* __restrict__ x, const ushort_t* __restrict__ W1B,
    const float* __restrict__ a_src, const float* __restrict__ a_dst,
    ushort_t* __restrict__ xs1b, float* __restrict__ as1, float* __restrict__ ad1, int N)
{
    __shared__ ushort_t lx[64 * 264];          // 256+8 pad: 2-way bank alias only
    const int tid = threadIdx.x;
    const int row0 = blockIdx.x * 64;
    const int nrows = min(64, N - row0);

    for (int i = tid; i < nrows * 32; i += 256) {
        int r = i >> 5, c = i & 31;
        const float* p = x + (size_t)(row0 + r) * IN_DIM + c * 8;
        float4 v0 = *(const float4*)p;
        float4 v1 = *(const float4*)(p + 4);
        ushort_t o[8] = { f2b(v0.x), f2b(v0.y), f2b(v0.z), f2b(v0.w),
                          f2b(v1.x), f2b(v1.y), f2b(v1.z), f2b(v1.w) };
        *(uint4*)(&lx[r * 264 + c * 8]) = *(uint4*)o;
    }
    __syncthreads();

    const int wave = tid >> 6, lane = tid & 63;
    const int lo = lane & 15, q = lane >> 4;
    f32x4 acc[8];
    #pragma unroll
    for (int t = 0; t < 8; t++) acc[t] = (f32x4){0.f, 0.f, 0.f, 0.f};

    const int arow = wave * 16 + lo;
    #pragma unroll
    for (int s = 0; s < 8; s++) {
        short8 af = *(const short8*)(&lx[arow * 264 + s * 32 + q * 8]);
        #pragma unroll
        for (int t = 0; t < 8; t++) {
            short8 bf = *(const short8*)(W1B + ((size_t)(s * 8 + t) * 64 + lane) * 8);
            acc[t] = __builtin_amdgcn_mfma_f32_16x16x32_bf16(af, bf, acc[t], 0, 0, 0);
        }
    }

    // attention logits: vs[m] = sum_n xs1[m][n]*a_src[n].  C layout: row=q*4+r, col=lo.
    float asv[8], adv[8];
    #pragma unroll
    for (int t = 0; t < 8; t++) { asv[t] = a_src[t * 16 + lo]; adv[t] = a_dst[t * 16 + lo]; }
    #pragma unroll
    for (int r = 0; r < 4; r++) {
        float vs = 0.f, vd = 0.f;
        #pragma unroll
        for (int t = 0; t < 8; t++) { vs += acc[t][r] * asv[t]; vd += acc[t][r] * adv[t]; }
        #pragma unroll
        for (int off = 1; off < 16; off <<= 1) {       // reduce over lo (stays in q-group)
            vs += __shfl_xor(vs, off, 64);
            vd += __shfl_xor(vd, off, 64);
        }
        int m = row0 + wave * 16 + q * 4 + r;
        if (lo == 0 && m < N) { as1[m] = vs; ad1[m] = vd; }
    }

    #pragma unroll
    for (int r = 0; r < 4; r++) {
        int m = row0 + wave * 16 + q * 4 + r;
        if (m < N) {
            #pragma unroll
            for (int t = 0; t < 8; t++)
                xs1b[(size_t)m * HID + t * 16 + lo] = f2b(acc[t][r]);
        }
    }
}

// ---------------------------------------------------------------------------
// gemm3g (MFMA): h3 = elu( g @ W2^T ) [N,32]x[32,128]; K=32; bf16 out.
// ---------------------------------------------------------------------------
__global__ __launch_bounds__(256) void gemm3g_mfma(
    const ushort_t* __restrict__ gb, const ushort_t* __restrict__ W2TB,
    ushort_t* __restrict__ h3b, int N)
{
    __shared__ ushort_t lh[64 * 40];           // 32+8 pad
    const int tid = threadIdx.x;
    const int row0 = blockIdx.x * 64;
    const int nrows = min(64, N - row0);
    for (int i = tid; i < nrows * 4; i += 256) {
        int r = i >> 2, c = i & 3;
        *(uint4*)(&lh[r * 40 + c * 8]) =
            *(const uint4*)(gb + (size_t)(row0 + r) * OUTD + c * 8);
    }
    __syncthreads();

    const int wave = tid >> 6, lane = tid & 63;
    const int lo = lane & 15, q = lane >> 4;
    f32x4 acc[8];
    #pragma unroll
    for (int t = 0; t < 8; t++) acc[t] = (f32x4){0.f, 0.f, 0.f, 0.f};
    short8 af = *(const short8*)(&lh[(wave * 16 + lo) * 40 + q * 8]);
    #pragma unroll
    for (int t = 0; t < 8; t++) {
        short8 bf = *(const short8*)(W2TB + ((size_t)t * 64 + lane) * 8);
        acc[t] = __builtin_amdgcn_mfma_f32_16x16x32_bf16(af, bf, acc[t], 0, 0, 0);
    }
    #pragma unroll
    for (int r = 0; r < 4; r++) {
        int m = row0 + wave * 16 + q * 4 + r;
        if (m < N) {
            #pragma unroll
            for (int t = 0; t < 8; t++) {
                float v = acc[t][r];
                v = v > 0.f ? v : expm1f(v);
                h3b[(size_t)m * HID + t * 16 + lo] = f2b(v);
            }
        }
    }
}

// ---------------------------------------------------------------------------
// gemm4 (MFMA): h4 = h3 @ W1^T [N,128]x[128,256]
// ---------------------------------------------------------------------------
__global__ __launch_bounds__(256) void gemm4_mfma(
    const ushort_t* __restrict__ h3b, const ushort_t* __restrict__ W1TB,
    float* __restrict__ h4, int N)
{
    __shared__ ushort_t lh[64 * 136];          // 128+8 pad
    const int tid = threadIdx.x;
    const int row0 = blockIdx.x * 64;
    const int nrows = min(64, N - row0);
    for (int i = tid; i < nrows * 16; i += 256) {
        int r = i >> 4, c = i & 15;
        *(uint4*)(&lh[r * 136 + c * 8]) =
            *(const uint4*)(h3b + (size_t)(row0 + r) * HID + c * 8);
    }
    __syncthreads();

    const int wave = tid >> 6, lane = tid & 63;
    const int lo = lane & 15, q = lane >> 4;
    f32x4 acc[16];
    #pragma unroll
    for (int t = 0; t < 16; t++) acc[t] = (f32x4){0.f, 0.f, 0.f, 0.f};
    const int arow = wave * 16 + lo;
    #pragma unroll
    for (int s = 0; s < 4; s++) {
        short8 af = *(const short8*)(&lh[arow * 136 + s * 32 + q * 8]);
        #pragma unroll
        for (int t = 0; t < 16; t++) {
            short8 bf = *(const short8*)(W1TB + ((size_t)(s * 16 + t) * 64 + lane) * 8);
            acc[t] = __builtin_amdgcn_mfma_f32_16x16x32_bf16(af, bf, acc[t], 0, 0, 0);
        }
    }
    #pragma unroll
    for (int r = 0; r < 4; r++) {
        int m = row0 + wave * 16 + q * 4 + r;
        if (m < N) {
            #pragma unroll
            for (int t = 0; t < 16; t++)
                h4[(size_t)m * IN_DIM + t * 16 + lo] = acc[t][r];
        }
    }
}

// ---------------------------------------------------------------------------
// Bucket-binned CSR build. bsort computes raw edge weights (one lane/edge),
// per-dst sums in LDS, and writes winv[d]=1/sum; aggs scale once at the end.
// ---------------------------------------------------------------------------
__global__ __launch_bounds__(256) void bhist_kernel(
    const int* __restrict__ dst, int* __restrict__ bcnt, int E, int B)
{
    __shared__ int lcnt[512];                 // B <= 512 (N <= 131072)
    int t = threadIdx.x;
    for (int i = t; i < B; i += 256) lcnt[i] = 0;
    __syncthreads();
    int base = blockIdx.x * EPB;
    int end = min(base + EPB, E);
    for (int e = base + t; e < end; e += 256)
        atomicAdd(&lcnt[dst[e] >> BSH], 1);
    __syncthreads();
    for (int i = t; i < B; i += 256) {
        int c = lcnt[i];
        if (c) atomicAdd(&bcnt[i], c);
    }
}

__global__ __launch_bounds__(512) void bscan_kernel(
    const int* __restrict__ bcnt, int* __restrict__ boff, int* __restrict__ gcur,
    int* __restrict__ off, int B, int N, int E)
{
    __shared__ int l[512];
    int t = threadIdx.x;
    int v = (t < B) ? bcnt[t] : 0;
    l[t] = v;
    __syncthreads();
    for (int o = 1; o < 512; o <<= 1) {
        int u = (t >= o) ? l[t - o] : 0;
        __syncthreads();
        l[t] += u;
        __syncthreads();
    }
    int pre = l[t] - v;                        // exclusive prefix
    if (t < B) { boff[t] = pre; gcur[t] = pre; }
    if (t == B - 1) boff[B] = pre + v;         // == E
    if (t == 0) off[N] = E;
}

__global__ __launch_bounds__(256) void bscatter_kernel(
    const int* __restrict__ src, const int* __restrict__ dst,
    int* __restrict__ gcur, int2* __restrict__ barr, int E, int B)
{
    __shared__ int lpos[512];
    int t = threadIdx.x;
    for (int i = t; i < B; i += 256) lpos[i] = 0;
    __syncthreads();
    int base = blockIdx.x * EPB;
    int end = min(base + EPB, E);
    for (int e = base + t; e < end; e += 256)
        atomicAdd(&lpos[dst[e] >> BSH], 1);
    __syncthreads();
    for (int i = t; i < B; i += 256) {
        int c = lpos[i];
        if (c) lpos[i] = atomicAdd(&gcur[i], c);   // count -> reserved base
    }
    __syncthreads();
    for (int e = base + t; e < end; e += 256) {
        int s = src[e], d = dst[e];
        int p = atomicAdd(&lpos[d >> BSH], 1);
        barr[p] = make_int2(s, d);
    }
}

__global__ __launch_bounds__(256) void bsort_kernel(
    const int2* __restrict__ barr, const int* __restrict__ boff,
    const float* __restrict__ as1, const float* __restrict__ ad1,
    int* __restrict__ off, int2* __restrict__ epk, float* __restrict__ winv, int N)
{
    __shared__ int ldeg[256];
    __shared__ int lscan[256];
    __shared__ float lsum[256];
    int b = blockIdx.x, t = threadIdx.x;
    int d0 = b << BSH;
    int e0 = boff[b], e1 = boff[b + 1];
    ldeg[t] = 0;
    lsum[t] = 0.f;
    __syncthreads();
    for (int e = e0 + t; e < e1; e += 256)
        atomicAdd(&ldeg[barr[e].y & 255], 1);
    __syncthreads();
    int my = ldeg[t];
    lscan[t] = my;
    __syncthreads();
    for (int o = 1; o < 256; o <<= 1) {
        int u = (t >= o) ? lscan[t - o] : 0;
        __syncthreads();
        lscan[t] += u;
        __syncthreads();
    }
    int pre = lscan[t] - my;                   // exclusive prefix within bucket
    int d = d0 + t;
    if (d < N) off[d] = e0 + pre;
    ldeg[t] = pre;                             // reuse as scatter cursor
    __syncthreads();
    for (int e = e0 + t; e < e1; e += 256) {
        int2 r = barr[e];
        float v = as1[r.x] + ad1[r.y];
        v = v > 0.f ? v : NEG_SLOPE * v;
        float w = __expf(v);                   // no max-subtraction: logits O(1)
        int p = atomicAdd(&ldeg[r.y & 255], 1);
        epk[e0 + p] = make_int2(r.x, __float_as_int(w));
        atomicAdd(&lsum[r.y & 255], w);        // ds_add_f32
    }
    __syncthreads();
    if (d < N) {
        float s = lsum[t];
        winv[d] = (my > 0 && s > 0.f) ? 1.0f / s : 0.f;
    }
}

// dot2 helper: acc += pr(bf16x2) . wpair(bf16x2)
#define DOT2(ACC, U0, U1, WP, SEL) do {                                     \
    uint_t pr_ = __builtin_amdgcn_perm((U0), (U1), (SEL));                  \
    asm("v_dot2_f32_bf16 %0, %1, %2, %0" : "+v"(ACC) : "v"(pr_), "v"(WP));  \
} while (0)

// ---------------------------------------------------------------------------
// agg1 (128 cols): wave per dst; 4 edge-groups x 16 lanes. QUAD loop: two
// pairs (e,e+1) and (e+8,e+9) loaded up front -> 6 independent VMEM in
// flight per group (2x MLP vs pair loop). v_dot2_f32_bf16 = 2 MACs/instr.
// Weights raw; normalize once via winv[d]. Fused elu; f32 out.
// ---------------------------------------------------------------------------
__global__ __launch_bounds__(256) void agg128_kernel(
    const ushort_t* __restrict__ xsb, const int* __restrict__ off,
    const int2* __restrict__ epk, const float* __restrict__ winv,
    float* __restrict__ outf, int N)
{
    int d = blockIdx.x * 4 + (threadIdx.x >> 6);
    if (d >= N) return;
    const int lane = threadIdx.x & 63;
    const int g = lane >> 4, li = lane & 15;
    const int e0 = off[d], e1 = off[d + 1];
    const float wi = winv[d];

    float acc[8];
    #pragma unroll
    for (int j = 0; j < 8; j++) acc[j] = 0.f;

    int e = e0 + 2 * g;
    // quad loop: 4 edges per group per iteration, all loads issued before compute
    for (; e + 9 < e1; e += 16) {
        int4_u ppA = *(const int4_u*)(epk + e);          // (s0,w0,s1,w1)
        int4_u ppB = *(const int4_u*)(epk + e + 8);      // (s2,w2,s3,w3)
        uint4 u0a = *(const uint4*)(xsb + (size_t)ppA.x * HID + li * 8);
        uint4 u1a = *(const uint4*)(xsb + (size_t)ppA.z * HID + li * 8);
        uint4 u0b = *(const uint4*)(xsb + (size_t)ppB.x * HID + li * 8);
        uint4 u1b = *(const uint4*)(xsb + (size_t)ppB.z * HID + li * 8);
        uint_t wpa, wpb;
        asm("v_cvt_pk_bf16_f32 %0, %1, %2"
            : "=v"(wpa) : "v"(__int_as_float(ppA.y)), "v"(__int_as_float(ppA.w)));
        asm("v_cvt_pk_bf16_f32 %0, %1, %2"
            : "=v"(wpb) : "v"(__int_as_float(ppB.y)), "v"(__int_as_float(ppB.w)));
        DOT2(acc[0], u0a.x, u1a.x, wpa, 0x01000504u);
        DOT2(acc[1], u0a.x, u1a.x, wpa, 0x03020706u);
        DOT2(acc[2], u0a.y, u1a.y, wpa, 0x01000504u);
        DOT2(acc[3], u0a.y, u1a.y, wpa, 0x03020706u);
        DOT2(acc[4], u0a.z, u1a.z, wpa, 0x01000504u);
        DOT2(acc[5], u0a.z, u1a.z, wpa, 0x03020706u);
        DOT2(acc[6], u0a.w, u1a.w, wpa, 0x01000504u);
        DOT2(acc[7], u0a.w, u1a.w, wpa, 0x03020706u);
        DOT2(acc[0], u0b.x, u1b.x, wpb, 0x01000504u);
        DOT2(acc[1], u0b.x, u1b.x, wpb, 0x03020706u);
        DOT2(acc[2], u0b.y, u1b.y, wpb, 0x01000504u);
        DOT2(acc[3], u0b.y, u1b.y, wpb, 0x03020706u);
        DOT2(acc[4], u0b.z, u1b.z, wpb, 0x01000504u);
        DOT2(acc[5], u0b.z, u1b.z, wpb, 0x03020706u);
        DOT2(acc[6], u0b.w, u1b.w, wpb, 0x01000504u);
        DOT2(acc[7], u0b.w, u1b.w, wpb, 0x03020706u);
    }
    // pair tail
    for (; e + 1 < e1; e += 8) {
        int4_u pp = *(const int4_u*)(epk + e);
        uint_t wpair;
        asm("v_cvt_pk_bf16_f32 %0, %1, %2"
            : "=v"(wpair) : "v"(__int_as_float(pp.y)), "v"(__int_as_float(pp.w)));
        uint4 u0 = *(const uint4*)(xsb + (size_t)pp.x * HID + li * 8);
        uint4 u1 = *(const uint4*)(xsb + (size_t)pp.z * HID + li * 8);
        DOT2(acc[0], u0.x, u1.x, wpair, 0x01000504u);
        DOT2(acc[1], u0.x, u1.x, wpair, 0x03020706u);
        DOT2(acc[2], u0.y, u1.y, wpair, 0x01000504u);
        DOT2(acc[3], u0.y, u1.y, wpair, 0x03020706u);
        DOT2(acc[4], u0.z, u1.z, wpair, 0x01000504u);
        DOT2(acc[5], u0.z, u1.z, wpair, 0x03020706u);
        DOT2(acc[6], u0.w, u1.w, wpair, 0x01000504u);
        DOT2(acc[7], u0.w, u1.w, wpair, 0x03020706u);
    }
    // single tail
    if (e < e1) {
        int2 p0 = epk[e];
        float w0 = __int_as_float(p0.y);
        uint4 u0 = *(const uint4*)(xsb + (size_t)p0.x * HID + li * 8);
        acc[0] += w0 * __uint_as_float(u0.x << 16);
        acc[1] += w0 * __uint_as_float(u0.x & 0xFFFF0000u);
        acc[2] += w0 * __uint_as_float(u0.y << 16);
        acc[3] += w0 * __uint_as_float(u0.y & 0xFFFF0000u);
        acc[4] += w0 * __uint_as_float(u0.z << 16);
        acc[5] += w0 * __uint_as_float(u0.z & 0xFFFF0000u);
        acc[6] += w0 * __uint_as_float(u0.w << 16);
        acc[7] += w0 * __uint_as_float(u0.w & 0xFFFF0000u);
    }

    #pragma unroll
    for (int j = 0; j < 8; j++) {
        acc[j] += __shfl_xor(acc[j], 16, 64);
        acc[j] += __shfl_xor(acc[j], 32, 64);
    }
    if (g != 0) return;
    float o[8];
    #pragma unroll
    for (int j = 0; j < 8; j++) {
        float v = acc[j] * wi;
        o[j] = v > 0.f ? v : expm1f(v);
    }
    float4 o0 = make_float4(o[0], o[1], o[2], o[3]);
    float4 o1 = make_float4(o[4], o[5], o[6], o[7]);
    *(float4*)(outf + (size_t)d * HID + li * 8) = o0;
    *(float4*)(outf + (size_t)d * HID + li * 8 + 4) = o1;
}

// ---------------------------------------------------------------------------
// agg2 (32 cols, on h2): wave per dst; 16 edge-groups x 4 lanes (uint4 each).
// Raw weights + winv scale. Output g (bf16) feeds gemm3g. No elu here.
// ---------------------------------------------------------------------------
__global__ __launch_bounds__(256) void agg32_kernel(
    const ushort_t* __restrict__ h2b, const int* __restrict__ off,
    const int2* __restrict__ epk, const float* __restrict__ winv,
    ushort_t* __restrict__ gb, int N)
{
    int d = blockIdx.x * 4 + (threadIdx.x >> 6);
    if (d >= N) return;
    const int lane = threadIdx.x & 63;
    const int g = lane >> 2, li = lane & 3;
    const int e0 = off[d], e1 = off[d + 1];
    const float wi = winv[d];

    float acc[8];
    #pragma unroll
    for (int j = 0; j < 8; j++) acc[j] = 0.f;

    for (int e = e0 + g; e < e1; e += 16) {
        int2 p = epk[e];
        float w = __int_as_float(p.y);
        uint4 u = *(const uint4*)(h2b + (size_t)p.x * OUTD + li * 8);
        acc[0] += w * __uint_as_float(u.x << 16);
        acc[1] += w * __uint_as_float(u.x & 0xFFFF0000u);
        acc[2] += w * __uint_as_float(u.y << 16);
        acc[3] += w * __uint_as_float(u.y & 0xFFFF0000u);
        acc[4] += w * __uint_as_float(u.z << 16);
        acc[5] += w * __uint_as_float(u.z & 0xFFFF0000u);
        acc[6] += w * __uint_as_float(u.w << 16);
        acc[7] += w * __uint_as_float(u.w & 0xFFFF0000u);
    }

    #pragma unroll
    for (int j = 0; j < 8; j++) {
        acc[j] += __shfl_xor(acc[j], 4, 64);
        acc[j] += __shfl_xor(acc[j], 8, 64);
        acc[j] += __shfl_xor(acc[j], 16, 64);
        acc[j] += __shfl_xor(acc[j], 32, 64);
    }
    if (g != 0) return;
    ushort_t ob[8] = { f2b(acc[0] * wi), f2b(acc[1] * wi), f2b(acc[2] * wi), f2b(acc[3] * wi),
                       f2b(acc[4] * wi), f2b(acc[5] * wi), f2b(acc[6] * wi), f2b(acc[7] * wi) };
    *(uint4*)(gb + (size_t)d * OUTD + li * 8) = *(uint4*)ob;
}

// ---------------------------------------------------------------------------
// gemm2: h2 = h1 @ W2 [N,128]x[128,32], f32 (accuracy) + bf16 copy for agg2
// ---------------------------------------------------------------------------
__global__ __launch_bounds__(256) void gemm2_kernel(
    const float* __restrict__ h1, const float* __restrict__ W2,
    float* __restrict__ h2, ushort_t* __restrict__ h2b, int N)
{
    __shared__ float lh[32 * 129];
    const int tid = threadIdx.x;
    const int row0 = blockIdx.x * 32;
    const int nrows = min(32, N - row0);
    for (int i = tid; i < nrows * 32; i += 256) {
        int r = i >> 5, q = i & 31;
        float4 v = *(const float4*)(h1 + (size_t)(row0 + r) * HID + q * 4);
        float* d = &lh[r * 129 + q * 4];
        d[0] = v.x; d[1] = v.y; d[2] = v.z; d[3] = v.w;
    }
    __syncthreads();
    const int r = tid >> 3;
    const int c0 = (tid & 7) * 4;
    float a0 = 0, a1 = 0, a2 = 0, a3 = 0;
    for (int k = 0; k < HID; k++) {
        float h = lh[r * 129 + k];
        float4 w = *(const float4*)(W2 + k * OUTD + c0);
        a0 += h * w.x; a1 += h * w.y; a2 += h * w.z; a3 += h * w.w;
    }
    if (r < nrows) {
        float4 o; o.x = a0; o.y = a1; o.z = a2; o.w = a3;
        *(float4*)(h2 + (size_t)(row0 + r) * OUTD + c0) = o;
        ushort_t ob[4] = { f2b(a0), f2b(a1), f2b(a2), f2b(a3) };
        *(uint2*)(h2b + (size_t)(row0 + r) * OUTD + c0) = *(uint2*)ob;
    }
}

extern "C" void kernel_launch(void* const* d_in, const int* in_sizes, int n_in,
                              void* d_out, int out_size, void* d_ws, size_t ws_size,
                              hipStream_t stream)
{
    const float* x     = (const float*)d_in[0];
    const float* W1    = (const float*)d_in[1];
    const float* a_src = (const float*)d_in[2];
    const float* a_dst = (const float*)d_in[3];
    const float* W2    = (const float*)d_in[4];
    const int*   ei    = (const int*)d_in[5];

    const int N = in_sizes[0] / IN_DIM;
    const int E = in_sizes[5] / 2;
    const int* src = ei;
    const int* dst = ei + E;
    const int B = (N + 255) >> BSH;            // buckets of 256 dst nodes

    float* ws = (float*)d_ws;
    size_t o = 0;
    ushort_t* A   = (ushort_t*)(ws + o); o += (size_t)N * HID / 2;   // xs1b; later gb
    float* Bb  = ws + o; o += (size_t)N * HID;        // h1 (f32)
    float* as1 = ws + o; o += N;
    float* ad1 = ws + o; o += N;
    float* winv = ws + o; o += N;
    ushort_t* h3b  = (ushort_t*)(ws + o); o += (size_t)N * HID / 2;   // bf16 h3
    ushort_t* h2b  = (ushort_t*)(ws + o); o += (size_t)N * OUTD / 2;  // bf16 h2
    ushort_t* W1B  = (ushort_t*)(ws + o); o += 16384;
    ushort_t* W1TB = (ushort_t*)(ws + o); o += 16384;
    ushort_t* W2TB = (ushort_t*)(ws + o); o += 2048;
    int2* barr = (int2*)(ws + o); o += (size_t)E * 2;  // packed (src,dst)
    int2* epk  = (int2*)(ws + o); o += (size_t)E * 2;  // packed (src, w_raw)
    int* off  = (int*)(ws + o);
    int* bcnt = off + N + 1;
    int* boff = bcnt + B;
    int* gcur = boff + B + 1;

    float* h2 = (float*)d_out;                 // [N,32]
    float* h4 = h2 + (size_t)N * OUTD;         // [N,256]

    hipMemsetAsync(bcnt, 0, (size_t)B * sizeof(int), stream);

    swz_kernel<<<(69632 + 255) / 256, 256, 0, stream>>>(W1, W2, W1B, W1TB, W2TB);

    // gemm1 (produces as1/ad1 needed by bsort) + bucket binning
    gemm1_mfma<<<(N + 63) / 64, 256, 0, stream>>>(x, W1B, a_src, a_dst, A, as1, ad1, N);

    const int GB = (E + EPB - 1) / EPB;
    bhist_kernel<<<GB, 256, 0, stream>>>(dst, bcnt, E, B);
    bscan_kernel<<<1, 512, 0, stream>>>(bcnt, boff, gcur, off, B, N, E);
    bscatter_kernel<<<GB, 256, 0, stream>>>(src, dst, gcur, barr, E, B);
    bsort_kernel<<<B, 256, 0, stream>>>(barr, boff, as1, ad1, off, epk, winv, N);

    // conv1 aggregate -> h1 (f32), gemm2 -> h2 (f32 out) + h2b (bf16)
    agg128_kernel<<<(N + 3) / 4, 256, 0, stream>>>(A, off, epk, winv, Bb, N);
    gemm2_kernel<<<(N + 31) / 32, 256, 0, stream>>>(Bb, W2, h2, h2b, N);

    // conv3: aggregate h2 (32 cols) -> g, then h3 = elu(g @ W2^T), gemm4 -> h4
    ushort_t* gb = A;                          // xs1b dead after agg128
    agg32_kernel<<<(N + 3) / 4, 256, 0, stream>>>(h2b, off, epk, winv, gb, N);
    gemm3g_mfma<<<(N + 63) / 64, 256, 0, stream>>>(gb, W2TB, h3b, N);
    gemm4_mfma<<<(N + 63) / 64, 256, 0, stream>>>(h3b, W1TB, h4, N);
}

// Round 9
// 447.279 us; speedup vs baseline: 1.1124x; 1.0979x over previous
//
#include <hip/hip_runtime.h>
#include <math.h>

#define IN_DIM 256
#define HID 128
#define OUTD 32
#define NEG_SLOPE 0.2f
#define BSH 8                 // 256 dst nodes per bucket
#define EPB 4096              // edges per binning block

typedef unsigned short ushort_t;
typedef unsigned int uint_t;
typedef __attribute__((ext_vector_type(8))) short short8;
typedef __attribute__((ext_vector_type(4))) float f32x4;
typedef int int4_u __attribute__((ext_vector_type(4), aligned(8)));  // 8B-aligned 2x epk record

__device__ __forceinline__ ushort_t f2b(float f) {
    union { float f; uint_t i; } v; v.f = f;
    uint_t x = v.i;
    uint_t r = (x + 0x7FFFu + ((x >> 16) & 1u)) >> 16;   // RNE
    return (ushort_t)r;
}

__device__ __forceinline__ float b2f(ushort_t b) {
    union { uint_t i; float f; } v; v.i = ((uint_t)b) << 16;
    return v.f;
}

// ---------------------------------------------------------------------------
// swizzle weights into MFMA B-fragment order (bf16).
// B-frag layout for 16x16x32: lane l holds B[k][n], n=16*tile+(l&15), k=32*step+(l>>4)*8+j
// W1B : B=W1   [256][128] -> 8 steps x 8 tiles   (32768)
// W1TB: B=W1^T [128][256] -> 4 steps x 16 tiles  (32768)
// W2TB: B=W2^T [32][128]  -> 1 step  x 8 tiles   (4096)
// W2B : B=W2   [128][32]  -> 4 steps x 2 tiles   (4096)
// ---------------------------------------------------------------------------
__global__ __launch_bounds__(256) void swz_kernel(
    const float* __restrict__ W1, const float* __restrict__ W2,
    ushort_t* __restrict__ W1B, ushort_t* __restrict__ W1TB,
    ushort_t* __restrict__ W2TB, ushort_t* __restrict__ W2B)
{
    int idx = blockIdx.x * 256 + threadIdx.x;
    if (idx < 32768) {
        int j = idx & 7, l = (idx >> 3) & 63, t = (idx >> 9) & 7, s = idx >> 12;
        int n = 16 * t + (l & 15), k = 32 * s + (l >> 4) * 8 + j;
        W1B[idx] = f2b(W1[k * HID + n]);
    } else if (idx < 65536) {
        int o = idx - 32768;
        int j = o & 7, l = (o >> 3) & 63, t = (o >> 9) & 15, s = o >> 13;
        int n = 16 * t + (l & 15), k = 32 * s + (l >> 4) * 8 + j;
        W1TB[o] = f2b(W1[n * HID + k]);
    } else if (idx < 69632) {
        int o = idx - 65536;
        int j = o & 7, l = (o >> 3) & 63, t = o >> 9;
        int n = 16 * t + (l & 15), k = (l >> 4) * 8 + j;
        W2TB[o] = f2b(W2[n * OUTD + k]);
    } else if (idx < 73728) {
        int o = idx - 69632;
        int j = o & 7, l = (o >> 3) & 63, t = (o >> 9) & 1, s = o >> 10;
        int n = 16 * t + (l & 15), k = 32 * s + (l >> 4) * 8 + j;
        W2B[o] = f2b(W2[k * OUTD + n]);
    }
}

// ---------------------------------------------------------------------------
// gemm1 (MFMA): xs1 = x @ W1 [N,256]x[256,128] + fused as1/ad1 attention dots.
// f32 x converted to bf16 during LDS staging; bf16 xs1 out.
// ---------------------------------------------------------------------------
__global__ __launch_bounds__(256) void gemm1_mfma(
    const float* __restrict__ x, const ushort_t* __restrict__ W1B,
    const float* __restrict__ a_src, const float* __restrict__ a_dst,
    ushort_t* __restrict__ xs1b, float* __restrict__ as1, float* __restrict__ ad1, int N)
{
    __shared__ ushort_t lx[64 * 264];          // 256+8 pad: 2-way bank alias only
    const int tid = threadIdx.x;
    const int row0 = blockIdx.x * 64;
    const int nrows = min(64, N - row0);

    for (int i = tid; i < nrows * 32; i += 256) {
        int r = i >> 5, c = i & 31;
        const float* p = x + (size_t)(row0 + r) * IN_DIM + c * 8;
        float4 v0 = *(const float4*)p;
        float4 v1 = *(const float4*)(p + 4);
        ushort_t o[8] = { f2b(v0.x), f2b(v0.y), f2b(v0.z), f2b(v0.w),
                          f2b(v1.x), f2b(v1.y), f2b(v1.z), f2b(v1.w) };
        *(uint4*)(&lx[r * 264 + c * 8]) = *(uint4*)o;
    }
    __syncthreads();

    const int wave = tid >> 6, lane = tid & 63;
    const int lo = lane & 15, q = lane >> 4;
    f32x4 acc[8];
    #pragma unroll
    for (int t = 0; t < 8; t++) acc[t] = (f32x4){0.f, 0.f, 0.f, 0.f};

    const int arow = wave * 16 + lo;
    #pragma unroll
    for (int s = 0; s < 8; s++) {
        short8 af = *(const short8*)(&lx[arow * 264 + s * 32 + q * 8]);
        #pragma unroll
        for (int t = 0; t < 8; t++) {
            short8 bf = *(const short8*)(W1B + ((size_t)(s * 8 + t) * 64 + lane) * 8);
            acc[t] = __builtin_amdgcn_mfma_f32_16x16x32_bf16(af, bf, acc[t], 0, 0, 0);
        }
    }

    // attention logits: vs[m] = sum_n xs1[m][n]*a_src[n].  C layout: row=q*4+r, col=lo.
    float asv[8], adv[8];
    #pragma unroll
    for (int t = 0; t < 8; t++) { asv[t] = a_src[t * 16 + lo]; adv[t] = a_dst[t * 16 + lo]; }
    #pragma unroll
    for (int r = 0; r < 4; r++) {
        float vs = 0.f, vd = 0.f;
        #pragma unroll
        for (int t = 0; t < 8; t++) { vs += acc[t][r] * asv[t]; vd += acc[t][r] * adv[t]; }
        #pragma unroll
        for (int off = 1; off < 16; off <<= 1) {       // reduce over lo (stays in q-group)
            vs += __shfl_xor(vs, off, 64);
            vd += __shfl_xor(vd, off, 64);
        }
        int m = row0 + wave * 16 + q * 4 + r;
        if (lo == 0 && m < N) { as1[m] = vs; ad1[m] = vd; }
    }

    #pragma unroll
    for (int r = 0; r < 4; r++) {
        int m = row0 + wave * 16 + q * 4 + r;
        if (m < N) {
            #pragma unroll
            for (int t = 0; t < 8; t++)
                xs1b[(size_t)m * HID + t * 16 + lo] = f2b(acc[t][r]);
        }
    }
}

// ---------------------------------------------------------------------------
// gemm2 (MFMA): h2 = h1 @ W2 [N,128]x[128,32]; f32 h2 (output) + bf16 h2b.
// Replaces the scalar gemm2: that one re-read W2 from L2 per k-step
// (~1.6 GB of L2 traffic total); MFMA form reads a 8 KB swizzled W2B.
// ---------------------------------------------------------------------------
__global__ __launch_bounds__(256) void gemm2_mfma(
    const ushort_t* __restrict__ h1b, const ushort_t* __restrict__ W2B,
    float* __restrict__ h2, ushort_t* __restrict__ h2b, int N)
{
    __shared__ ushort_t lh[64 * 136];          // 128+8 pad
    const int tid = threadIdx.x;
    const int row0 = blockIdx.x * 64;
    const int nrows = min(64, N - row0);
    for (int i = tid; i < nrows * 16; i += 256) {
        int r = i >> 4, c = i & 15;
        *(uint4*)(&lh[r * 136 + c * 8]) =
            *(const uint4*)(h1b + (size_t)(row0 + r) * HID + c * 8);
    }
    __syncthreads();

    const int wave = tid >> 6, lane = tid & 63;
    const int lo = lane & 15, q = lane >> 4;
    f32x4 acc[2];
    acc[0] = (f32x4){0.f, 0.f, 0.f, 0.f};
    acc[1] = (f32x4){0.f, 0.f, 0.f, 0.f};
    const int arow = wave * 16 + lo;
    #pragma unroll
    for (int s = 0; s < 4; s++) {
        short8 af = *(const short8*)(&lh[arow * 136 + s * 32 + q * 8]);
        #pragma unroll
        for (int t = 0; t < 2; t++) {
            short8 bf = *(const short8*)(W2B + ((size_t)(s * 2 + t) * 64 + lane) * 8);
            acc[t] = __builtin_amdgcn_mfma_f32_16x16x32_bf16(af, bf, acc[t], 0, 0, 0);
        }
    }
    #pragma unroll
    for (int r = 0; r < 4; r++) {
        int m = row0 + wave * 16 + q * 4 + r;
        if (m < N) {
            #pragma unroll
            for (int t = 0; t < 2; t++) {
                float v = acc[t][r];
                h2[(size_t)m * OUTD + t * 16 + lo] = v;
                h2b[(size_t)m * OUTD + t * 16 + lo] = f2b(v);
            }
        }
    }
}

// ---------------------------------------------------------------------------
// gemm3g (MFMA): h3 = elu( g @ W2^T ) [N,32]x[32,128]; K=32; bf16 out.
// ---------------------------------------------------------------------------
__global__ __launch_bounds__(256) void gemm3g_mfma(
    const ushort_t* __restrict__ gb, const ushort_t* __restrict__ W2TB,
    ushort_t* __restrict__ h3b, int N)
{
    __shared__ ushort_t lh[64 * 40];           // 32+8 pad
    const int tid = threadIdx.x;
    const int row0 = blockIdx.x * 64;
    const int nrows = min(64, N - row0);
    for (int i = tid; i < nrows * 4; i += 256) {
        int r = i >> 2, c = i & 3;
        *(uint4*)(&lh[r * 40 + c * 8]) =
            *(const uint4*)(gb + (size_t)(row0 + r) * OUTD + c * 8);
    }
    __syncthreads();

    const int wave = tid >> 6, lane = tid & 63;
    const int lo = lane & 15, q = lane >> 4;
    f32x4 acc[8];
    #pragma unroll
    for (int t = 0; t < 8; t++) acc[t] = (f32x4){0.f, 0.f, 0.f, 0.f};
    short8 af = *(const short8*)(&lh[(wave * 16 + lo) * 40 + q * 8]);
    #pragma unroll
    for (int t = 0; t < 8; t++) {
        short8 bf = *(const short8*)(W2TB + ((size_t)t * 64 + lane) * 8);
        acc[t] = __builtin_amdgcn_mfma_f32_16x16x32_bf16(af, bf, acc[t], 0, 0, 0);
    }
    #pragma unroll
    for (int r = 0; r < 4; r++) {
        int m = row0 + wave * 16 + q * 4 + r;
        if (m < N) {
            #pragma unroll
            for (int t = 0; t < 8; t++) {
                float v = acc[t][r];
                v = v > 0.f ? v : expm1f(v);
                h3b[(size_t)m * HID + t * 16 + lo] = f2b(v);
            }
        }
    }
}

// ---------------------------------------------------------------------------
// gemm4 (MFMA): h4 = h3 @ W1^T [N,128]x[128,256]
// ---------------------------------------------------------------------------
__global__ __launch_bounds__(256) void gemm4_mfma(
    const ushort_t* __restrict__ h3b, const ushort_t* __restrict__ W1TB,
    float* __restrict__ h4, int N)
{
    __shared__ ushort_t lh[64 * 136];          // 128+8 pad
    const int tid = threadIdx.x;
    const int row0 = blockIdx.x * 64;
    const int nrows = min(64, N - row0);
    for (int i = tid; i < nrows * 16; i += 256) {
        int r = i >> 4, c = i & 15;
        *(uint4*)(&lh[r * 136 + c * 8]) =
            *(const uint4*)(h3b + (size_t)(row0 + r) * HID + c * 8);
    }
    __syncthreads();

    const int wave = tid >> 6, lane = tid & 63;
    const int lo = lane & 15, q = lane >> 4;
    f32x4 acc[16];
    #pragma unroll
    for (int t = 0; t < 16; t++) acc[t] = (f32x4){0.f, 0.f, 0.f, 0.f};
    const int arow = wave * 16 + lo;
    #pragma unroll
    for (int s = 0; s < 4; s++) {
        short8 af = *(const short8*)(&lh[arow * 136 + s * 32 + q * 8]);
        #pragma unroll
        for (int t = 0; t < 16; t++) {
            short8 bf = *(const short8*)(W1TB + ((size_t)(s * 16 + t) * 64 + lane) * 8);
            acc[t] = __builtin_amdgcn_mfma_f32_16x16x32_bf16(af, bf, acc[t], 0, 0, 0);
        }
    }
    #pragma unroll
    for (int r = 0; r < 4; r++) {
        int m = row0 + wave * 16 + q * 4 + r;
        if (m < N) {
            #pragma unroll
            for (int t = 0; t < 16; t++)
                h4[(size_t)m * IN_DIM + t * 16 + lo] = acc[t][r];
        }
    }
}

// ---------------------------------------------------------------------------
// Bucket-binned CSR build. bsort computes raw edge weights (one lane/edge),
// per-dst sums in LDS, and writes winv[d]=1/sum; aggs scale once at the end.
// ---------------------------------------------------------------------------
__global__ __launch_bounds__(256) void bhist_kernel(
    const int* __restrict__ dst, int* __restrict__ bcnt, int E, int B)
{
    __shared__ int lcnt[512];                 // B <= 512 (N <= 131072)
    int t = threadIdx.x;
    for (int i = t; i < B; i += 256) lcnt[i] = 0;
    __syncthreads();
    int base = blockIdx.x * EPB;
    int end = min(base + EPB, E);
    for (int e = base + t; e < end; e += 256)
        atomicAdd(&lcnt[dst[e] >> BSH], 1);
    __syncthreads();
    for (int i = t; i < B; i += 256) {
        int c = lcnt[i];
        if (c) atomicAdd(&bcnt[i], c);
    }
}

__global__ __launch_bounds__(512) void bscan_kernel(
    const int* __restrict__ bcnt, int* __restrict__ boff, int* __restrict__ gcur,
    int* __restrict__ off, int B, int N, int E)
{
    __shared__ int l[512];
    int t = threadIdx.x;
    int v = (t < B) ? bcnt[t] : 0;
    l[t] = v;
    __syncthreads();
    for (int o = 1; o < 512; o <<= 1) {
        int u = (t >= o) ? l[t - o] : 0;
        __syncthreads();
        l[t] += u;
        __syncthreads();
    }
    int pre = l[t] - v;                        // exclusive prefix
    if (t < B) { boff[t] = pre; gcur[t] = pre; }
    if (t == B - 1) boff[B] = pre + v;         // == E
    if (t == 0) off[N] = E;
}

__global__ __launch_bounds__(256) void bscatter_kernel(
    const int* __restrict__ src, const int* __restrict__ dst,
    int* __restrict__ gcur, int2* __restrict__ barr, int E, int B)
{
    __shared__ int lpos[512];
    int t = threadIdx.x;
    for (int i = t; i < B; i += 256) lpos[i] = 0;
    __syncthreads();
    int base = blockIdx.x * EPB;
    int end = min(base + EPB, E);
    for (int e = base + t; e < end; e += 256)
        atomicAdd(&lpos[dst[e] >> BSH], 1);
    __syncthreads();
    for (int i = t; i < B; i += 256) {
        int c = lpos[i];
        if (c) lpos[i] = atomicAdd(&gcur[i], c);   // count -> reserved base
    }
    __syncthreads();
    for (int e = base + t; e < end; e += 256) {
        int s = src[e], d = dst[e];
        int p = atomicAdd(&lpos[d >> BSH], 1);
        barr[p] = make_int2(s, d);
    }
}

__global__ __launch_bounds__(256) void bsort_kernel(
    const int2* __restrict__ barr, const int* __restrict__ boff,
    const float* __restrict__ as1, const float* __restrict__ ad1,
    int* __restrict__ off, int2* __restrict__ epk, float* __restrict__ winv, int N)
{
    __shared__ int ldeg[256];
    __shared__ int lscan[256];
    __shared__ float lsum[256];
    int b = blockIdx.x, t = threadIdx.x;
    int d0 = b << BSH;
    int e0 = boff[b], e1 = boff[b + 1];
    ldeg[t] = 0;
    lsum[t] = 0.f;
    __syncthreads();
    for (int e = e0 + t; e < e1; e += 256)
        atomicAdd(&ldeg[barr[e].y & 255], 1);
    __syncthreads();
    int my = ldeg[t];
    lscan[t] = my;
    __syncthreads();
    for (int o = 1; o < 256; o <<= 1) {
        int u = (t >= o) ? lscan[t - o] : 0;
        __syncthreads();
        lscan[t] += u;
        __syncthreads();
    }
    int pre = lscan[t] - my;                   // exclusive prefix within bucket
    int d = d0 + t;
    if (d < N) off[d] = e0 + pre;
    ldeg[t] = pre;                             // reuse as scatter cursor
    __syncthreads();
    for (int e = e0 + t; e < e1; e += 256) {
        int2 r = barr[e];
        float v = as1[r.x] + ad1[r.y];
        v = v > 0.f ? v : NEG_SLOPE * v;
        float w = __expf(v);                   // no max-subtraction: logits O(1)
        int p = atomicAdd(&ldeg[r.y & 255], 1);
        epk[e0 + p] = make_int2(r.x, __float_as_int(w));
        atomicAdd(&lsum[r.y & 255], w);        // ds_add_f32
    }
    __syncthreads();
    if (d < N) {
        float s = lsum[t];
        winv[d] = (my > 0 && s > 0.f) ? 1.0f / s : 0.f;
    }
}

// dot2 helper: acc += pr(bf16x2) . wpair(bf16x2)
#define DOT2(ACC, U0, U1, WP, SEL) do {                                     \
    uint_t pr_ = __builtin_amdgcn_perm((U0), (U1), (SEL));                  \
    asm("v_dot2_f32_bf16 %0, %1, %2, %0" : "+v"(ACC) : "v"(pr_), "v"(WP));  \
} while (0)

// ---------------------------------------------------------------------------
// agg1 (128 cols): wave per dst; 4 edge-groups x 16 lanes. Quad loop (2 pairs
// in flight). At the random-gather fabric ceiling (~3.5 TB/s L2-miss) per R6-R8
// evidence. bf16 out (h1b, feeds MFMA gemm2); fused elu; winv normalization.
// ---------------------------------------------------------------------------
__global__ __launch_bounds__(256) void agg128_kernel(
    const ushort_t* __restrict__ xsb, const int* __restrict__ off,
    const int2* __restrict__ epk, const float* __restrict__ winv,
    ushort_t* __restrict__ outb, int N)
{
    int d = blockIdx.x * 4 + (threadIdx.x >> 6);
    if (d >= N) return;
    const int lane = threadIdx.x & 63;
    const int g = lane >> 4, li = lane & 15;
    const int e0 = off[d], e1 = off[d + 1];
    const float wi = winv[d];

    float acc[8];
    #pragma unroll
    for (int j = 0; j < 8; j++) acc[j] = 0.f;

    int e = e0 + 2 * g;
    // quad loop: 4 edges per group per iteration, all loads issued before compute
    for (; e + 9 < e1; e += 16) {
        int4_u ppA = *(const int4_u*)(epk + e);          // (s0,w0,s1,w1)
        int4_u ppB = *(const int4_u*)(epk + e + 8);      // (s2,w2,s3,w3)
        uint4 u0a = *(const uint4*)(xsb + (size_t)ppA.x * HID + li * 8);
        uint4 u1a = *(const uint4*)(xsb + (size_t)ppA.z * HID + li * 8);
        uint4 u0b = *(const uint4*)(xsb + (size_t)ppB.x * HID + li * 8);
        uint4 u1b = *(const uint4*)(xsb + (size_t)ppB.z * HID + li * 8);
        uint_t wpa, wpb;
        asm("v_cvt_pk_bf16_f32 %0, %1, %2"
            : "=v"(wpa) : "v"(__int_as_float(ppA.y)), "v"(__int_as_float(ppA.w)));
        asm("v_cvt_pk_bf16_f32 %0, %1, %2"
            : "=v"(wpb) : "v"(__int_as_float(ppB.y)), "v"(__int_as_float(ppB.w)));
        DOT2(acc[0], u0a.x, u1a.x, wpa, 0x01000504u);
        DOT2(acc[1], u0a.x, u1a.x, wpa, 0x03020706u);
        DOT2(acc[2], u0a.y, u1a.y, wpa, 0x01000504u);
        DOT2(acc[3], u0a.y, u1a.y, wpa, 0x03020706u);
        DOT2(acc[4], u0a.z, u1a.z, wpa, 0x01000504u);
        DOT2(acc[5], u0a.z, u1a.z, wpa, 0x03020706u);
        DOT2(acc[6], u0a.w, u1a.w, wpa, 0x01000504u);
        DOT2(acc[7], u0a.w, u1a.w, wpa, 0x03020706u);
        DOT2(acc[0], u0b.x, u1b.x, wpb, 0x01000504u);
        DOT2(acc[1], u0b.x, u1b.x, wpb, 0x03020706u);
        DOT2(acc[2], u0b.y, u1b.y, wpb, 0x01000504u);
        DOT2(acc[3], u0b.y, u1b.y, wpb, 0x03020706u);
        DOT2(acc[4], u0b.z, u1b.z, wpb, 0x01000504u);
        DOT2(acc[5], u0b.z, u1b.z, wpb, 0x03020706u);
        DOT2(acc[6], u0b.w, u1b.w, wpb, 0x01000504u);
        DOT2(acc[7], u0b.w, u1b.w, wpb, 0x03020706u);
    }
    // pair tail
    for (; e + 1 < e1; e += 8) {
        int4_u pp = *(const int4_u*)(epk + e);
        uint_t wpair;
        asm("v_cvt_pk_bf16_f32 %0, %1, %2"
            : "=v"(wpair) : "v"(__int_as_float(pp.y)), "v"(__int_as_float(pp.w)));
        uint4 u0 = *(const uint4*)(xsb + (size_t)pp.x * HID + li * 8);
        uint4 u1 = *(const uint4*)(xsb + (size_t)pp.z * HID + li * 8);
        DOT2(acc[0], u0.x, u1.x, wpair, 0x01000504u);
        DOT2(acc[1], u0.x, u1.x, wpair, 0x03020706u);
        DOT2(acc[2], u0.y, u1.y, wpair, 0x01000504u);
        DOT2(acc[3], u0.y, u1.y, wpair, 0x03020706u);
        DOT2(acc[4], u0.z, u1.z, wpair, 0x01000504u);
        DOT2(acc[5], u0.z, u1.z, wpair, 0x03020706u);
        DOT2(acc[6], u0.w, u1.w, wpair, 0x01000504u);
        DOT2(acc[7], u0.w, u1.w, wpair, 0x03020706u);
    }
    // single tail
    if (e < e1) {
        int2 p0 = epk[e];
        float w0 = __int_as_float(p0.y);
        uint4 u0 = *(const uint4*)(xsb + (size_t)p0.x * HID + li * 8);
        acc[0] += w0 * __uint_as_float(u0.x << 16);
        acc[1] += w0 * __uint_as_float(u0.x & 0xFFFF0000u);
        acc[2] += w0 * __uint_as_float(u0.y << 16);
        acc[3] += w0 * __uint_as_float(u0.y & 0xFFFF0000u);
        acc[4] += w0 * __uint_as_float(u0.z << 16);
        acc[5] += w0 * __uint_as_float(u0.z & 0xFFFF0000u);
        acc[6] += w0 * __uint_as_float(u0.w << 16);
        acc[7] += w0 * __uint_as_float(u0.w & 0xFFFF0000u);
    }

    #pragma unroll
    for (int j = 0; j < 8; j++) {
        acc[j] += __shfl_xor(acc[j], 16, 64);
        acc[j] += __shfl_xor(acc[j], 32, 64);
    }
    if (g != 0) return;
    ushort_t ob[8];
    #pragma unroll
    for (int j = 0; j < 8; j++) {
        float v = acc[j] * wi;
        v = v > 0.f ? v : expm1f(v);
        ob[j] = f2b(v);
    }
    *(uint4*)(outb + (size_t)d * HID + li * 8) = *(uint4*)ob;
}

// ---------------------------------------------------------------------------
// agg2 (32 cols, on h2): wave per dst; 16 edge-groups x 4 lanes (uint4 each).
// Raw weights + winv scale. Output g (bf16) feeds gemm3g. No elu here.
// ---------------------------------------------------------------------------
__global__ __launch_bounds__(256) void agg32_kernel(
    const ushort_t* __restrict__ h2b, const int* __restrict__ off,
    const int2* __restrict__ epk, const float* __restrict__ winv,
    ushort_t* __restrict__ gb, int N)
{
    int d = blockIdx.x * 4 + (threadIdx.x >> 6);
    if (d >= N) return;
    const int lane = threadIdx.x & 63;
    const int g = lane >> 2, li = lane & 3;
    const int e0 = off[d], e1 = off[d + 1];
    const float wi = winv[d];

    float acc[8];
    #pragma unroll
    for (int j = 0; j < 8; j++) acc[j] = 0.f;

    for (int e = e0 + g; e < e1; e += 16) {
        int2 p = epk[e];
        float w = __int_as_float(p.y);
        uint4 u = *(const uint4*)(h2b + (size_t)p.x * OUTD + li * 8);
        acc[0] += w * __uint_as_float(u.x << 16);
        acc[1] += w * __uint_as_float(u.x & 0xFFFF0000u);
        acc[2] += w * __uint_as_float(u.y << 16);
        acc[3] += w * __uint_as_float(u.y & 0xFFFF0000u);
        acc[4] += w * __uint_as_float(u.z << 16);
        acc[5] += w * __uint_as_float(u.z & 0xFFFF0000u);
        acc[6] += w * __uint_as_float(u.w << 16);
        acc[7] += w * __uint_as_float(u.w & 0xFFFF0000u);
    }

    #pragma unroll
    for (int j = 0; j < 8; j++) {
        acc[j] += __shfl_xor(acc[j], 4, 64);
        acc[j] += __shfl_xor(acc[j], 8, 64);
        acc[j] += __shfl_xor(acc[j], 16, 64);
        acc[j] += __shfl_xor(acc[j], 32, 64);
    }
    if (g != 0) return;
    ushort_t ob[8] = { f2b(acc[0] * wi), f2b(acc[1] * wi), f2b(acc[2] * wi), f2b(acc[3] * wi),
                       f2b(acc[4] * wi), f2b(acc[5] * wi), f2b(acc[6] * wi), f2b(acc[7] * wi) };
    *(uint4*)(gb + (size_t)d * OUTD + li * 8) = *(uint4*)ob;
}

extern "C" void kernel_launch(void* const* d_in, const int* in_sizes, int n_in,
                              void* d_out, int out_size, void* d_ws, size_t ws_size,
                              hipStream_t stream)
{
    const float* x     = (const float*)d_in[0];
    const float* W1    = (const float*)d_in[1];
    const float* a_src = (const float*)d_in[2];
    const float* a_dst = (const float*)d_in[3];
    const float* W2    = (const float*)d_in[4];
    const int*   ei    = (const int*)d_in[5];

    const int N = in_sizes[0] / IN_DIM;
    const int E = in_sizes[5] / 2;
    const int* src = ei;
    const int* dst = ei + E;
    const int B = (N + 255) >> BSH;            // buckets of 256 dst nodes

    float* ws = (float*)d_ws;
    size_t o = 0;
    ushort_t* A    = (ushort_t*)(ws + o); o += (size_t)N * HID / 2;   // xs1b; later gb
    ushort_t* h1b  = (ushort_t*)(ws + o); o += (size_t)N * HID / 2;   // bf16 h1
    float* as1 = ws + o; o += N;
    float* ad1 = ws + o; o += N;
    float* winv = ws + o; o += N;
    ushort_t* h3b  = (ushort_t*)(ws + o); o += (size_t)N * HID / 2;   // bf16 h3
    ushort_t* h2b  = (ushort_t*)(ws + o); o += (size_t)N * OUTD / 2;  // bf16 h2
    ushort_t* W1B  = (ushort_t*)(ws + o); o += 16384;
    ushort_t* W1TB = (ushort_t*)(ws + o); o += 16384;
    ushort_t* W2TB = (ushort_t*)(ws + o); o += 2048;
    ushort_t* W2B  = (ushort_t*)(ws + o); o += 2048;
    int2* barr = (int2*)(ws + o); o += (size_t)E * 2;  // packed (src,dst)
    int2* epk  = (int2*)(ws + o); o += (size_t)E * 2;  // packed (src, w_raw)
    int* off  = (int*)(ws + o);
    int* bcnt = off + N + 1;
    int* boff = bcnt + B;
    int* gcur = boff + B + 1;

    float* h2 = (float*)d_out;                 // [N,32]
    float* h4 = h2 + (size_t)N * OUTD;         // [N,256]

    hipMemsetAsync(bcnt, 0, (size_t)B * sizeof(int), stream);

    swz_kernel<<<(73728 + 255) / 256, 256, 0, stream>>>(W1, W2, W1B, W1TB, W2TB, W2B);

    // gemm1 (produces as1/ad1 needed by bsort) + bucket binning
    gemm1_mfma<<<(N + 63) / 64, 256, 0, stream>>>(x, W1B, a_src, a_dst, A, as1, ad1, N);

    const int GB = (E + EPB - 1) / EPB;
    bhist_kernel<<<GB, 256, 0, stream>>>(dst, bcnt, E, B);
    bscan_kernel<<<1, 512, 0, stream>>>(bcnt, boff, gcur, off, B, N, E);
    bscatter_kernel<<<GB, 256, 0, stream>>>(src, dst, gcur, barr, E, B);
    bsort_kernel<<<B, 256, 0, stream>>>(barr, boff, as1, ad1, off, epk, winv, N);

    // conv1 aggregate -> h1 (bf16), gemm2 (MFMA) -> h2 (f32 out) + h2b (bf16)
    agg128_kernel<<<(N + 3) / 4, 256, 0, stream>>>(A, off, epk, winv, h1b, N);
    gemm2_mfma<<<(N + 63) / 64, 256, 0, stream>>>(h1b, W2B, h2, h2b, N);

    // conv3: aggregate h2 (32 cols) -> g, then h3 = elu(g @ W2^T), gemm4 -> h4
    ushort_t* gb = A;                          // xs1b dead after agg128
    agg32_kernel<<<(N + 3) / 4, 256, 0, stream>>>(h2b, off, epk, winv, gb, N);
    gemm3g_mfma<<<(N + 63) / 64, 256, 0, stream>>>(gb, W2TB, h3b, N);
    gemm4_mfma<<<(N + 63) / 64, 256, 0, stream>>>(h3b, W1TB, h4, N);
}